// Round 3
// baseline (643.217 us; speedup 1.0000x reference)
//
#include <hip/hip_runtime.h>
#include <hip/hip_bf16.h>

typedef __attribute__((ext_vector_type(8))) short bf16x8;
typedef __attribute__((ext_vector_type(4))) float f32x4;

#define HDIM 512
#define BM 128
#define BN 256
#define BK 64
#define BKP 72   // +8 bf16 pad -> row stride 144 B (16B-aligned)

__device__ __forceinline__ unsigned short f2bf(float f) {
  unsigned u = __float_as_uint(f);
  u += 0x7fffu + ((u >> 16) & 1u);   // round-to-nearest-even
  return (unsigned short)(u >> 16);
}

__device__ __forceinline__ unsigned int pk_bf(float x, float y) {
  __hip_bfloat162 h = __float22bfloat162_rn(float2{x, y});
  union { __hip_bfloat162 b; unsigned int u; } cv; cv.b = h;
  return cv.u;
}

// w1 [1024][512] fp32 -> w1t [512][1024] bf16; also zeroes cnt[0..nzero)
__global__ void k_w1t(const float* __restrict__ w1, unsigned short* __restrict__ w1t,
                      int* __restrict__ cnt, int nzero) {
  int idx = blockIdx.x * 256 + threadIdx.x;   // exactly 1024*512 threads
  int k = idx >> 9;
  int n = idx & 511;
  w1t[n * 1024 + k] = f2bf(w1[idx]);
  if (idx < nzero) cnt[idx] = 0;
}

// histogram of edge cols
__global__ void k_hist(const int* __restrict__ ec, int* __restrict__ cnt, int E) {
  int e = blockIdx.x * 256 + threadIdx.x;
  if (e < E) atomicAdd(&cnt[ec[e]], 1);
}

// exclusive scan of cnt[0..n) -> ptr[0..n], and cur copy. Single block, 1024 thr.
__global__ __launch_bounds__(1024) void k_scan(const int* __restrict__ cnt, int* __restrict__ ptr,
                                               int* __restrict__ cur, int n) {
  __shared__ int wsum[16];
  __shared__ int carry_s;
  const int tid = threadIdx.x, lane = tid & 63, w = tid >> 6;
  if (tid == 0) carry_s = 0;
  __syncthreads();
  for (int base = 0; base < n; base += 1024) {
    int i = base + tid;
    int x = (i < n) ? cnt[i] : 0;
    int v = x;
    #pragma unroll
    for (int off = 1; off < 64; off <<= 1) {
      int t = __shfl_up(v, off, 64);
      if (lane >= off) v += t;
    }
    if (lane == 63) wsum[w] = v;
    __syncthreads();
    int wpre = 0;
    #pragma unroll
    for (int j = 0; j < 16; ++j) { int s = wsum[j]; if (j < w) wpre += s; }
    int carry = carry_s;
    __syncthreads();
    int incl = v + wpre;
    if (i < n) { int excl = carry + incl - x; ptr[i] = excl; cur[i] = excl; }
    if (tid == 1023) carry_s = carry + incl;
    __syncthreads();
  }
  if (threadIdx.x == 0) ptr[n] = carry_s;
}

// scatter edges into movie buckets
__global__ void k_scatter(const int* __restrict__ er, const int* __restrict__ ec,
                          int* __restrict__ cur, int* __restrict__ srow,
                          int* __restrict__ seid, int E) {
  int e = blockIdx.x * 256 + threadIdx.x;
  if (e < E) {
    int c = ec[e];
    int pos = atomicAdd(&cur[c], 1);
    srow[pos] = er[e];
    seid[pos] = e;
  }
}

// C[M,512](bf16) = A[M,512](fp32) @ w1t^T slice  (bf16 MFMA, fp32 acc)
__global__ __launch_bounds__(512) void k_gemm(const float* __restrict__ A, int M,
    const unsigned short* __restrict__ w1t, int koff,
    unsigned short* __restrict__ C)
{
  __shared__ unsigned short As[BM][BKP];   // 18 KB
  __shared__ unsigned short Bs[BN][BKP];   // 36 KB
  const int tid  = threadIdx.x;
  const int lane = tid & 63;
  const int wid  = tid >> 6;                  // 0..7
  const int wm = wid & 1, wn = wid >> 1;      // 2 x 4 wave grid
  const int lm = lane & 15, lq = lane >> 4;
  const int nbase = blockIdx.x * BN;
  const int mbase = blockIdx.y * BM;

  f32x4 acc[4][4];
  #pragma unroll
  for (int i = 0; i < 4; ++i)
    #pragma unroll
    for (int j = 0; j < 4; ++j) acc[i][j] = (f32x4){0.f, 0.f, 0.f, 0.f};

  for (int kb = 0; kb < HDIM / BK; ++kb) {
    const int k0 = kb * BK;
    __syncthreads();
    #pragma unroll
    for (int i = 0; i < 4; ++i) {
      int fid = i * 512 + tid;
      int r = fid >> 4, c4 = fid & 15;
      int row = mbase + r; if (row > M - 1) row = M - 1;
      const float4 v = *(const float4*)&A[(size_t)row * HDIM + k0 + c4 * 4];
      unsigned int* dst = (unsigned int*)&As[r][c4 * 4];
      dst[0] = pk_bf(v.x, v.y);
      dst[1] = pk_bf(v.z, v.w);
    }
    #pragma unroll
    for (int i = 0; i < 4; ++i) {
      int cid = i * 512 + tid;
      int r = cid >> 3, c8 = cid & 7;
      const bf16x8 g = *(const bf16x8*)&w1t[(size_t)(nbase + r) * 1024 + koff + k0 + c8 * 8];
      *(bf16x8*)&Bs[r][c8 * 8] = g;
    }
    __syncthreads();
    #pragma unroll
    for (int ks = 0; ks < 2; ++ks) {
      bf16x8 af[4], bfr[4];
      #pragma unroll
      for (int t = 0; t < 4; ++t) {
        af[t]  = *(const bf16x8*)&As[wm * 64 + t * 16 + lm][ks * 32 + lq * 8];
        bfr[t] = *(const bf16x8*)&Bs[wn * 64 + t * 16 + lm][ks * 32 + lq * 8];
      }
      #pragma unroll
      for (int mi = 0; mi < 4; ++mi)
        #pragma unroll
        for (int ni = 0; ni < 4; ++ni)
          acc[mi][ni] = __builtin_amdgcn_mfma_f32_16x16x32_bf16(af[mi], bfr[ni], acc[mi][ni], 0, 0, 0);
    }
  }
  #pragma unroll
  for (int mi = 0; mi < 4; ++mi)
    #pragma unroll
    for (int ni = 0; ni < 4; ++ni)
      #pragma unroll
      for (int r = 0; r < 4; ++r) {
        int rg = mbase + wm * 64 + mi * 16 + lq * 4 + r;
        int cg = nbase + wn * 64 + ni * 16 + lm;
        if (rg < M) C[(size_t)rg * HDIM + cg] = f2bf(acc[mi][ni][r]);
      }
}

__device__ __forceinline__ float edot(const uint4 ua, const float* vb, const float* wv) {
  float p = 0.f, s;
  s = __uint_as_float(ua.x << 16)         + vb[0]; s = fmaxf(s, 0.f); p += s * wv[0];
  s = __uint_as_float(ua.x & 0xffff0000u) + vb[1]; s = fmaxf(s, 0.f); p += s * wv[1];
  s = __uint_as_float(ua.y << 16)         + vb[2]; s = fmaxf(s, 0.f); p += s * wv[2];
  s = __uint_as_float(ua.y & 0xffff0000u) + vb[3]; s = fmaxf(s, 0.f); p += s * wv[3];
  s = __uint_as_float(ua.z << 16)         + vb[4]; s = fmaxf(s, 0.f); p += s * wv[4];
  s = __uint_as_float(ua.z & 0xffff0000u) + vb[5]; s = fmaxf(s, 0.f); p += s * wv[5];
  s = __uint_as_float(ua.w << 16)         + vb[6]; s = fmaxf(s, 0.f); p += s * wv[6];
  s = __uint_as_float(ua.w & 0xffff0000u) + vb[7]; s = fmaxf(s, 0.f); p += s * wv[7];
  return p;
}

// movie-grouped edge phase: one wave per movie, M[c]+b1 folded once, gather U per edge
__global__ __launch_bounds__(256) void k_edge_g(const int* __restrict__ ptr,
    const int* __restrict__ srow, const int* __restrict__ seid,
    const unsigned short* __restrict__ u1, const unsigned short* __restrict__ m1,
    const float* __restrict__ b1, const float* __restrict__ w2, const float* __restrict__ b2,
    float* __restrict__ out, int nmov)
{
  const int lane = threadIdx.x & 63;
  const int gw = blockIdx.x * 4 + (threadIdx.x >> 6);
  const int nw = gridDim.x * 4;
  const float4 b1a = *(const float4*)&b1[lane * 8];
  const float4 b1b = *(const float4*)&b1[lane * 8 + 4];
  const float4 w2a = *(const float4*)&w2[lane * 8];
  const float4 w2b = *(const float4*)&w2[lane * 8 + 4];
  float wv[8] = {w2a.x, w2a.y, w2a.z, w2a.w, w2b.x, w2b.y, w2b.z, w2b.w};
  const float bias2 = b2[0];
  for (int c = gw; c < nmov; c += nw) {
    const int beg = ptr[c], end = ptr[c + 1];
    if (beg == end) continue;
    const uint4 va = *(const uint4*)&m1[(size_t)c * HDIM + lane * 8];
    float vb[8];
    vb[0] = __uint_as_float(va.x << 16)         + b1a.x;
    vb[1] = __uint_as_float(va.x & 0xffff0000u) + b1a.y;
    vb[2] = __uint_as_float(va.y << 16)         + b1a.z;
    vb[3] = __uint_as_float(va.y & 0xffff0000u) + b1a.w;
    vb[4] = __uint_as_float(va.z << 16)         + b1b.x;
    vb[5] = __uint_as_float(va.z & 0xffff0000u) + b1b.y;
    vb[6] = __uint_as_float(va.w << 16)         + b1b.z;
    vb[7] = __uint_as_float(va.w & 0xffff0000u) + b1b.w;
    int i = beg;
    for (; i + 1 < end; i += 2) {
      const int r0 = srow[i], r1 = srow[i + 1];
      const int e0 = seid[i], e1 = seid[i + 1];
      const uint4 ua0 = *(const uint4*)&u1[(size_t)r0 * HDIM + lane * 8];
      const uint4 ua1 = *(const uint4*)&u1[(size_t)r1 * HDIM + lane * 8];
      float p0 = edot(ua0, vb, wv);
      float p1 = edot(ua1, vb, wv);
      #pragma unroll
      for (int off = 32; off > 0; off >>= 1) {
        p0 += __shfl_down(p0, off, 64);
        p1 += __shfl_down(p1, off, 64);
      }
      if (lane == 0) { out[e0] = p0 + bias2; out[e1] = p1 + bias2; }
    }
    if (i < end) {
      const int r0 = srow[i], e0 = seid[i];
      const uint4 ua0 = *(const uint4*)&u1[(size_t)r0 * HDIM + lane * 8];
      float p0 = edot(ua0, vb, wv);
      #pragma unroll
      for (int off = 32; off > 0; off >>= 1) p0 += __shfl_down(p0, off, 64);
      if (lane == 0) out[e0] = p0 + bias2;
    }
  }
}

// unsorted edge path (fallback if ws can't hold sort scratch)
__global__ __launch_bounds__(256) void k_edge(const int* __restrict__ er, const int* __restrict__ ec,
    const unsigned short* __restrict__ u1, const unsigned short* __restrict__ m1,
    const float* __restrict__ b1, const float* __restrict__ w2, const float* __restrict__ b2,
    float* __restrict__ out, int E)
{
  const int lane = threadIdx.x & 63;
  const int gwid = blockIdx.x * 4 + (threadIdx.x >> 6);
  const int nw   = gridDim.x * 4;
  const float4 b1a = *(const float4*)&b1[lane * 8];
  const float4 b1b = *(const float4*)&b1[lane * 8 + 4];
  const float4 w2a = *(const float4*)&w2[lane * 8];
  const float4 w2b = *(const float4*)&w2[lane * 8 + 4];
  float bv[8] = {b1a.x, b1a.y, b1a.z, b1a.w, b1b.x, b1b.y, b1b.z, b1b.w};
  float wv[8] = {w2a.x, w2a.y, w2a.z, w2a.w, w2b.x, w2b.y, w2b.z, w2b.w};
  const float bias2 = b2[0];
  for (int e = gwid; e < E; e += nw) {
    const int r = er[e], c = ec[e];
    const uint4 ua = *(const uint4*)&u1[(size_t)r * HDIM + lane * 8];
    const uint4 va = *(const uint4*)&m1[(size_t)c * HDIM + lane * 8];
    float vb[8];
    vb[0] = __uint_as_float(va.x << 16)         + bv[0];
    vb[1] = __uint_as_float(va.x & 0xffff0000u) + bv[1];
    vb[2] = __uint_as_float(va.y << 16)         + bv[2];
    vb[3] = __uint_as_float(va.y & 0xffff0000u) + bv[3];
    vb[4] = __uint_as_float(va.z << 16)         + bv[4];
    vb[5] = __uint_as_float(va.z & 0xffff0000u) + bv[5];
    vb[6] = __uint_as_float(va.w << 16)         + bv[6];
    vb[7] = __uint_as_float(va.w & 0xffff0000u) + bv[7];
    float p = edot(ua, vb, wv);
    #pragma unroll
    for (int off = 32; off > 0; off >>= 1) p += __shfl_down(p, off, 64);
    if (lane == 0) out[e] = p + bias2;
  }
}

// Correct-but-slow fp32 fallback (only if ws_size too small)
__global__ __launch_bounds__(256) void k_fallback(const float* __restrict__ zu, const float* __restrict__ zm,
    const int* __restrict__ er, const int* __restrict__ ec, const float* __restrict__ w1,
    const float* __restrict__ b1, const float* __restrict__ w2, const float* __restrict__ b2,
    float* __restrict__ out, int E)
{
  __shared__ float Zs[64][33];
  __shared__ float Ws[32][65];
  __shared__ float outacc[64];
  __shared__ int ridx[64], cidx[64];
  const int tid = threadIdx.x;
  const int ebase = blockIdx.x * 64;
  if (tid < 64) {
    int e = ebase + tid; if (e > E - 1) e = E - 1;
    ridx[tid] = er[e]; cidx[tid] = ec[e];
    outacc[tid] = 0.f;
  }
  const int tx = tid & 15, ty = tid >> 4;
  for (int nt = 0; nt < 8; ++nt) {
    float acc[4][4] = {};
    for (int kc = 0; kc < 32; ++kc) {
      __syncthreads();
      #pragma unroll
      for (int i = 0; i < 8; ++i) {
        int id = i * 256 + tid;
        int rr = id >> 5, cc = id & 31;
        int k = kc * 32 + cc;
        Zs[rr][cc] = (k < 512) ? zu[(size_t)ridx[rr] * 512 + k]
                               : zm[(size_t)cidx[rr] * 512 + (k - 512)];
      }
      #pragma unroll
      for (int i = 0; i < 8; ++i) {
        int id = i * 256 + tid;
        int kk = id >> 6, nn = id & 63;
        Ws[kk][nn] = w1[(size_t)(kc * 32 + kk) * 512 + nt * 64 + nn];
      }
      __syncthreads();
      #pragma unroll
      for (int kk = 0; kk < 32; ++kk) {
        float a0 = Zs[ty*4+0][kk], a1 = Zs[ty*4+1][kk], a2 = Zs[ty*4+2][kk], a3 = Zs[ty*4+3][kk];
        float q0 = Ws[kk][tx*4+0], q1 = Ws[kk][tx*4+1], q2 = Ws[kk][tx*4+2], q3 = Ws[kk][tx*4+3];
        acc[0][0] += a0*q0; acc[0][1] += a0*q1; acc[0][2] += a0*q2; acc[0][3] += a0*q3;
        acc[1][0] += a1*q0; acc[1][1] += a1*q1; acc[1][2] += a1*q2; acc[1][3] += a1*q3;
        acc[2][0] += a2*q0; acc[2][1] += a2*q1; acc[2][2] += a2*q2; acc[2][3] += a2*q3;
        acc[3][0] += a3*q0; acc[3][1] += a3*q1; acc[3][2] += a3*q2; acc[3][3] += a3*q3;
      }
    }
    #pragma unroll
    for (int i = 0; i < 4; ++i) {
      float p = 0.f;
      #pragma unroll
      for (int j = 0; j < 4; ++j) {
        int n = nt * 64 + tx * 4 + j;
        float h = acc[i][j] + b1[n]; h = fmaxf(h, 0.f);
        p += h * w2[n];
      }
      atomicAdd(&outacc[ty * 4 + i], p);
    }
  }
  __syncthreads();
  if (tid < 64 && (ebase + tid) < E) out[ebase + tid] = outacc[tid] + b2[0];
}

extern "C" void kernel_launch(void* const* d_in, const int* in_sizes, int n_in,
                              void* d_out, int out_size, void* d_ws, size_t ws_size,
                              hipStream_t stream)
{
  const float* z_user  = (const float*)d_in[0];
  const float* z_movie = (const float*)d_in[1];
  const int*   erow    = (const int*)d_in[2];
  const int*   ecol    = (const int*)d_in[3];
  const float* w1      = (const float*)d_in[4];
  const float* b1      = (const float*)d_in[5];
  const float* w2      = (const float*)d_in[6];
  const float* b2      = (const float*)d_in[7];
  float* out = (float*)d_out;

  const int NU = in_sizes[0] / HDIM;   // 100000
  const int NM = in_sizes[1] / HDIM;   // 50000
  const int E  = in_sizes[2];          // 500000

  const size_t shorts = (size_t)(NU + NM) * HDIM + (size_t)1024 * 512;
  const size_t need_basic  = shorts * 2;
  const size_t need_sorted = shorts * 2 + ((size_t)3 * NM + 1 + (size_t)2 * E) * 4;

  if (ws_size >= need_basic) {
    unsigned short* u1  = (unsigned short*)d_ws;
    unsigned short* m1  = u1 + (size_t)NU * HDIM;
    unsigned short* w1t = m1 + (size_t)NM * HDIM;
    if (ws_size >= need_sorted) {
      int* cnt  = (int*)(w1t + (size_t)1024 * 512);
      int* ptr  = cnt + NM;
      int* cur  = ptr + NM + 1;
      int* srow = cur + NM;
      int* seid = srow + E;
      k_w1t<<<(1024 * 512) / 256, 256, 0, stream>>>(w1, w1t, cnt, NM);
      k_hist<<<(E + 255) / 256, 256, 0, stream>>>(ecol, cnt, E);
      k_scan<<<1, 1024, 0, stream>>>(cnt, ptr, cur, NM);
      k_scatter<<<(E + 255) / 256, 256, 0, stream>>>(erow, ecol, cur, srow, seid, E);
      k_gemm<<<dim3(HDIM / BN, (NU + BM - 1) / BM), 512, 0, stream>>>(z_user,  NU, w1t, 0,   u1);
      k_gemm<<<dim3(HDIM / BN, (NM + BM - 1) / BM), 512, 0, stream>>>(z_movie, NM, w1t, 512, m1);
      k_edge_g<<<2048, 256, 0, stream>>>(ptr, srow, seid, u1, m1, b1, w2, b2, out, NM);
    } else {
      k_w1t<<<(1024 * 512) / 256, 256, 0, stream>>>(w1, w1t, (int*)d_ws, 0);
      k_gemm<<<dim3(HDIM / BN, (NU + BM - 1) / BM), 512, 0, stream>>>(z_user,  NU, w1t, 0,   u1);
      k_gemm<<<dim3(HDIM / BN, (NM + BM - 1) / BM), 512, 0, stream>>>(z_movie, NM, w1t, 512, m1);
      k_edge<<<2048, 256, 0, stream>>>(erow, ecol, u1, m1, b1, w2, b2, out, E);
    }
  } else {
    k_fallback<<<(E + 63) / 64, 256, 0, stream>>>(z_user, z_movie, erow, ecol, w1, b1, w2, b2, out, E);
  }
}

// Round 4
// 602.160 us; speedup vs baseline: 1.0682x; 1.0682x over previous
//
#include <hip/hip_runtime.h>
#include <hip/hip_bf16.h>

typedef __attribute__((ext_vector_type(8))) short bf16x8;
typedef __attribute__((ext_vector_type(4))) float f32x4;

#define HDIM 512
#define BM 128
#define BN 256
#define BK 64

__device__ __forceinline__ unsigned short f2bf(float f) {
  unsigned u = __float_as_uint(f);
  u += 0x7fffu + ((u >> 16) & 1u);   // round-to-nearest-even
  return (unsigned short)(u >> 16);
}

__device__ __forceinline__ unsigned int pk_bf(float x, float y) {
  __hip_bfloat162 h = __float22bfloat162_rn(float2{x, y});
  union { __hip_bfloat162 b; unsigned int u; } cv; cv.b = h;
  return cv.u;
}

__device__ __forceinline__ void glds16(const void* g, void* l) {
  __builtin_amdgcn_global_load_lds(
      (const __attribute__((address_space(1))) void*)g,
      (__attribute__((address_space(3))) void*)l, 16, 0, 0);
}

// w1 [1024][512] fp32 -> w1t [512][1024] bf16 (transposed); also zeroes cnt[0..nzero)
__global__ void k_w1t(const float* __restrict__ w1, unsigned short* __restrict__ w1t,
                      int* __restrict__ cnt, int nzero) {
  int idx = blockIdx.x * 256 + threadIdx.x;   // exactly 1024*512 threads
  int k = idx >> 9;
  int n = idx & 511;
  w1t[n * 1024 + k] = f2bf(w1[idx]);
  if (idx < nzero) cnt[idx] = 0;
}

// histogram of edge cols
__global__ void k_hist(const int* __restrict__ ec, int* __restrict__ cnt, int E) {
  int e = blockIdx.x * 256 + threadIdx.x;
  if (e < E) atomicAdd(&cnt[ec[e]], 1);
}

// hierarchical scan, stage 1: per-1024-chunk sums
__global__ __launch_bounds__(1024) void k_scan1(const int* __restrict__ cnt,
                                                int* __restrict__ bsum, int n) {
  __shared__ int ws[16];
  const int tid = threadIdx.x, lane = tid & 63, w = tid >> 6;
  int i = blockIdx.x * 1024 + tid;
  int x = (i < n) ? cnt[i] : 0;
  #pragma unroll
  for (int off = 32; off > 0; off >>= 1) x += __shfl_down(x, off, 64);
  if (lane == 0) ws[w] = x;
  __syncthreads();
  if (tid == 0) {
    int s = 0;
    #pragma unroll
    for (int j = 0; j < 16; ++j) s += ws[j];
    bsum[blockIdx.x] = s;
  }
}

// stage 2: exclusive scan of block sums (nb <= 64), writes total to ptr[n]
__global__ void k_scan2(int* __restrict__ bsum, int* __restrict__ ptr, int nb, int n) {
  const int tid = threadIdx.x;
  if (nb > 64) {               // safety fallback, never hit at NM=50000
    if (tid == 0) {
      int s = 0;
      for (int j = 0; j < nb; ++j) { int v = bsum[j]; bsum[j] = s; s += v; }
      ptr[n] = s;
    }
    return;
  }
  int x = (tid < nb) ? bsum[tid] : 0;
  int v = x;
  #pragma unroll
  for (int off = 1; off < 64; off <<= 1) {
    int t = __shfl_up(v, off, 64);
    if (tid >= off) v += t;
  }
  if (tid < nb) bsum[tid] = v - x;
  if (tid == 63) ptr[n] = v;
}

// stage 3: rescan chunk with block offset, write ptr & cur
__global__ __launch_bounds__(1024) void k_scan3(const int* __restrict__ cnt,
    const int* __restrict__ bsum, int* __restrict__ ptr, int* __restrict__ cur, int n) {
  __shared__ int ws[16];
  const int tid = threadIdx.x, lane = tid & 63, w = tid >> 6;
  int i = blockIdx.x * 1024 + tid;
  int x = (i < n) ? cnt[i] : 0;
  int v = x;
  #pragma unroll
  for (int off = 1; off < 64; off <<= 1) {
    int t = __shfl_up(v, off, 64);
    if (lane >= off) v += t;
  }
  if (lane == 63) ws[w] = v;
  __syncthreads();
  int wpre = 0;
  #pragma unroll
  for (int j = 0; j < 16; ++j) { int s = ws[j]; if (j < w) wpre += s; }
  int excl = bsum[blockIdx.x] + wpre + v - x;
  if (i < n) { ptr[i] = excl; cur[i] = excl; }
}

// scatter edges into movie buckets
__global__ void k_scatter(const int* __restrict__ er, const int* __restrict__ ec,
                          int* __restrict__ cur, int* __restrict__ srow,
                          int* __restrict__ seid, int E) {
  int e = blockIdx.x * 256 + threadIdx.x;
  if (e < E) {
    int c = ec[e];
    int pos = atomicAdd(&cur[c], 1);
    srow[pos] = er[e];
    seid[pos] = e;
  }
}

// C[M,512](bf16) = A[M,512](fp32) @ w1t^T slice  (bf16 MFMA, fp32 acc)
// m97-style: global_load_lds staging for A (fp32, XOR-swizzled) and B (bf16, XOR-swizzled).
// 512 threads = 8 waves, 2(M) x 4(N) wave grid, 64x64 per wave.
__global__ __launch_bounds__(512, 4) void k_gemm(const float* __restrict__ A, int M,
    const unsigned short* __restrict__ w1t, int koff,
    unsigned short* __restrict__ C)
{
  __shared__ float          As[BM * BK];   // 32 KB, granule-swizzled: (r, gr) holds col gr^(r&15)
  __shared__ unsigned short Bs[BN * BK];   // 32 KB, granule-swizzled: (r, gr) holds col gr^(r&7)
  const int tid  = threadIdx.x;
  const int lane = tid & 63;
  const int wid  = tid >> 6;                  // 0..7
  const int wuni = wid << 6;                  // wave-uniform lane-group base
  const int wm = wid & 1, wn = wid >> 1;      // 2 x 4 wave grid
  const int lm = lane & 15, lq = lane >> 4;
  const int nbase = blockIdx.x * BN;
  const int mbase = blockIdx.y * BM;

  f32x4 acc[4][4];
  #pragma unroll
  for (int i = 0; i < 4; ++i)
    #pragma unroll
    for (int j = 0; j < 4; ++j) acc[i][j] = (f32x4){0.f, 0.f, 0.f, 0.f};

  for (int kb = 0; kb < HDIM / BK; ++kb) {
    const int k0 = kb * BK;
    __syncthreads();   // previous compute done before overwriting LDS
    // stage A: 128 rows x 16 granules (16B = 4 fp32 each), swizzled
    #pragma unroll
    for (int i = 0; i < 4; ++i) {
      int G  = i * 512 + tid;          // per-lane granule id (0..2047)
      int Gw = i * 512 + wuni;         // wave-uniform LDS base granule
      int r = G >> 4, gr = G & 15;
      int row = mbase + r; if (row > M - 1) row = M - 1;
      int cg = gr ^ (r & 15);
      glds16(&A[(size_t)row * HDIM + k0 + cg * 4], (char*)As + (size_t)Gw * 16);
    }
    // stage B: 256 rows x 8 granules (16B = 8 bf16 each), swizzled
    #pragma unroll
    for (int i = 0; i < 4; ++i) {
      int G  = i * 512 + tid;          // 0..2047
      int Gw = i * 512 + wuni;
      int r = G >> 3, gr = G & 7;
      int cg = gr ^ (r & 7);
      glds16(&w1t[(size_t)(nbase + r) * 1024 + koff + k0 + cg * 8],
             (char*)Bs + (size_t)Gw * 16);
    }
    __syncthreads();   // drains vmcnt(0): glds complete
    #pragma unroll
    for (int ks = 0; ks < 2; ++ks) {
      // B frags: one swizzled granule each
      bf16x8 bfr[4];
      #pragma unroll
      for (int ni = 0; ni < 4; ++ni) {
        int R = wn * 64 + ni * 16 + lm;
        int g = (ks * 4 + lq) ^ (R & 7);
        bfr[ni] = *(const bf16x8*)&Bs[(size_t)(R * 8 + g) * 8];
      }
      #pragma unroll
      for (int mi = 0; mi < 4; ++mi) {
        int R = wm * 64 + mi * 16 + lm;
        int g0 = ks * 8 + lq * 2;
        int m  = R & 15;
        const float4 f0 = *(const float4*)&As[(size_t)(R * 16 + (g0 ^ m)) * 4];
        const float4 f1 = *(const float4*)&As[(size_t)(R * 16 + ((g0 + 1) ^ m)) * 4];
        union { unsigned int u[4]; bf16x8 v; } af;
        af.u[0] = pk_bf(f0.x, f0.y);
        af.u[1] = pk_bf(f0.z, f0.w);
        af.u[2] = pk_bf(f1.x, f1.y);
        af.u[3] = pk_bf(f1.z, f1.w);
        #pragma unroll
        for (int ni = 0; ni < 4; ++ni)
          acc[mi][ni] = __builtin_amdgcn_mfma_f32_16x16x32_bf16(af.v, bfr[ni], acc[mi][ni], 0, 0, 0);
      }
    }
  }
  // epilogue: C/D layout col=lane&15, row=(lane>>4)*4+reg  (m89-verified)
  #pragma unroll
  for (int mi = 0; mi < 4; ++mi)
    #pragma unroll
    for (int ni = 0; ni < 4; ++ni)
      #pragma unroll
      for (int r = 0; r < 4; ++r) {
        int rg = mbase + wm * 64 + mi * 16 + lq * 4 + r;
        int cg = nbase + wn * 64 + ni * 16 + lm;
        if (rg < M) C[(size_t)rg * HDIM + cg] = f2bf(acc[mi][ni][r]);
      }
}

__device__ __forceinline__ float edot(const uint4 ua, const float* vb, const float* wv) {
  float p = 0.f, s;
  s = __uint_as_float(ua.x << 16)         + vb[0]; s = fmaxf(s, 0.f); p += s * wv[0];
  s = __uint_as_float(ua.x & 0xffff0000u) + vb[1]; s = fmaxf(s, 0.f); p += s * wv[1];
  s = __uint_as_float(ua.y << 16)         + vb[2]; s = fmaxf(s, 0.f); p += s * wv[2];
  s = __uint_as_float(ua.y & 0xffff0000u) + vb[3]; s = fmaxf(s, 0.f); p += s * wv[3];
  s = __uint_as_float(ua.z << 16)         + vb[4]; s = fmaxf(s, 0.f); p += s * wv[4];
  s = __uint_as_float(ua.z & 0xffff0000u) + vb[5]; s = fmaxf(s, 0.f); p += s * wv[5];
  s = __uint_as_float(ua.w << 16)         + vb[6]; s = fmaxf(s, 0.f); p += s * wv[6];
  s = __uint_as_float(ua.w & 0xffff0000u) + vb[7]; s = fmaxf(s, 0.f); p += s * wv[7];
  return p;
}

// movie-grouped edge phase: one wave per movie, M[c]+b1 folded once, gather U per edge
__global__ __launch_bounds__(256) void k_edge_g(const int* __restrict__ ptr,
    const int* __restrict__ srow, const int* __restrict__ seid,
    const unsigned short* __restrict__ u1, const unsigned short* __restrict__ m1,
    const float* __restrict__ b1, const float* __restrict__ w2, const float* __restrict__ b2,
    float* __restrict__ out, int nmov)
{
  const int lane = threadIdx.x & 63;
  const int gw = blockIdx.x * 4 + (threadIdx.x >> 6);
  const int nw = gridDim.x * 4;
  const float4 b1a = *(const float4*)&b1[lane * 8];
  const float4 b1b = *(const float4*)&b1[lane * 8 + 4];
  const float4 w2a = *(const float4*)&w2[lane * 8];
  const float4 w2b = *(const float4*)&w2[lane * 8 + 4];
  float wv[8] = {w2a.x, w2a.y, w2a.z, w2a.w, w2b.x, w2b.y, w2b.z, w2b.w};
  const float bias2 = b2[0];
  for (int c = gw; c < nmov; c += nw) {
    const int beg = ptr[c], end = ptr[c + 1];
    if (beg == end) continue;
    const uint4 va = *(const uint4*)&m1[(size_t)c * HDIM + lane * 8];
    float vb[8];
    vb[0] = __uint_as_float(va.x << 16)         + b1a.x;
    vb[1] = __uint_as_float(va.x & 0xffff0000u) + b1a.y;
    vb[2] = __uint_as_float(va.y << 16)         + b1a.z;
    vb[3] = __uint_as_float(va.y & 0xffff0000u) + b1a.w;
    vb[4] = __uint_as_float(va.z << 16)         + b1b.x;
    vb[5] = __uint_as_float(va.z & 0xffff0000u) + b1b.y;
    vb[6] = __uint_as_float(va.w << 16)         + b1b.z;
    vb[7] = __uint_as_float(va.w & 0xffff0000u) + b1b.w;
    int i = beg;
    for (; i + 1 < end; i += 2) {
      const int r0 = srow[i], r1 = srow[i + 1];
      const int e0 = seid[i], e1 = seid[i + 1];
      const uint4 ua0 = *(const uint4*)&u1[(size_t)r0 * HDIM + lane * 8];
      const uint4 ua1 = *(const uint4*)&u1[(size_t)r1 * HDIM + lane * 8];
      float p0 = edot(ua0, vb, wv);
      float p1 = edot(ua1, vb, wv);
      #pragma unroll
      for (int off = 32; off > 0; off >>= 1) {
        p0 += __shfl_down(p0, off, 64);
        p1 += __shfl_down(p1, off, 64);
      }
      if (lane == 0) { out[e0] = p0 + bias2; out[e1] = p1 + bias2; }
    }
    if (i < end) {
      const int r0 = srow[i], e0 = seid[i];
      const uint4 ua0 = *(const uint4*)&u1[(size_t)r0 * HDIM + lane * 8];
      float p0 = edot(ua0, vb, wv);
      #pragma unroll
      for (int off = 32; off > 0; off >>= 1) p0 += __shfl_down(p0, off, 64);
      if (lane == 0) out[e0] = p0 + bias2;
    }
  }
}

// unsorted edge path (fallback if ws can't hold sort scratch)
__global__ __launch_bounds__(256) void k_edge(const int* __restrict__ er, const int* __restrict__ ec,
    const unsigned short* __restrict__ u1, const unsigned short* __restrict__ m1,
    const float* __restrict__ b1, const float* __restrict__ w2, const float* __restrict__ b2,
    float* __restrict__ out, int E)
{
  const int lane = threadIdx.x & 63;
  const int gwid = blockIdx.x * 4 + (threadIdx.x >> 6);
  const int nw   = gridDim.x * 4;
  const float4 b1a = *(const float4*)&b1[lane * 8];
  const float4 b1b = *(const float4*)&b1[lane * 8 + 4];
  const float4 w2a = *(const float4*)&w2[lane * 8];
  const float4 w2b = *(const float4*)&w2[lane * 8 + 4];
  float bv[8] = {b1a.x, b1a.y, b1a.z, b1a.w, b1b.x, b1b.y, b1b.z, b1b.w};
  float wv[8] = {w2a.x, w2a.y, w2a.z, w2a.w, w2b.x, w2b.y, w2b.z, w2b.w};
  const float bias2 = b2[0];
  for (int e = gwid; e < E; e += nw) {
    const int r = er[e], c = ec[e];
    const uint4 ua = *(const uint4*)&u1[(size_t)r * HDIM + lane * 8];
    const uint4 va = *(const uint4*)&m1[(size_t)c * HDIM + lane * 8];
    float vb[8];
    vb[0] = __uint_as_float(va.x << 16)         + bv[0];
    vb[1] = __uint_as_float(va.x & 0xffff0000u) + bv[1];
    vb[2] = __uint_as_float(va.y << 16)         + bv[2];
    vb[3] = __uint_as_float(va.y & 0xffff0000u) + bv[3];
    vb[4] = __uint_as_float(va.z << 16)         + bv[4];
    vb[5] = __uint_as_float(va.z & 0xffff0000u) + bv[5];
    vb[6] = __uint_as_float(va.w << 16)         + bv[6];
    vb[7] = __uint_as_float(va.w & 0xffff0000u) + bv[7];
    float p = edot(ua, vb, wv);
    #pragma unroll
    for (int off = 32; off > 0; off >>= 1) p += __shfl_down(p, off, 64);
    if (lane == 0) out[e] = p + bias2;
  }
}

// Correct-but-slow fp32 fallback (only if ws_size too small)
__global__ __launch_bounds__(256) void k_fallback(const float* __restrict__ zu, const float* __restrict__ zm,
    const int* __restrict__ er, const int* __restrict__ ec, const float* __restrict__ w1,
    const float* __restrict__ b1, const float* __restrict__ w2, const float* __restrict__ b2,
    float* __restrict__ out, int E)
{
  __shared__ float Zs[64][33];
  __shared__ float Ws[32][65];
  __shared__ float outacc[64];
  __shared__ int ridx[64], cidx[64];
  const int tid = threadIdx.x;
  const int ebase = blockIdx.x * 64;
  if (tid < 64) {
    int e = ebase + tid; if (e > E - 1) e = E - 1;
    ridx[tid] = er[e]; cidx[tid] = ec[e];
    outacc[tid] = 0.f;
  }
  const int tx = tid & 15, ty = tid >> 4;
  for (int nt = 0; nt < 8; ++nt) {
    float acc[4][4] = {};
    for (int kc = 0; kc < 32; ++kc) {
      __syncthreads();
      #pragma unroll
      for (int i = 0; i < 8; ++i) {
        int id = i * 256 + tid;
        int rr = id >> 5, cc = id & 31;
        int k = kc * 32 + cc;
        Zs[rr][cc] = (k < 512) ? zu[(size_t)ridx[rr] * 512 + k]
                               : zm[(size_t)cidx[rr] * 512 + (k - 512)];
      }
      #pragma unroll
      for (int i = 0; i < 8; ++i) {
        int id = i * 256 + tid;
        int kk = id >> 6, nn = id & 63;
        Ws[kk][nn] = w1[(size_t)(kc * 32 + kk) * 512 + nt * 64 + nn];
      }
      __syncthreads();
      #pragma unroll
      for (int kk = 0; kk < 32; ++kk) {
        float a0 = Zs[ty*4+0][kk], a1 = Zs[ty*4+1][kk], a2 = Zs[ty*4+2][kk], a3 = Zs[ty*4+3][kk];
        float q0 = Ws[kk][tx*4+0], q1 = Ws[kk][tx*4+1], q2 = Ws[kk][tx*4+2], q3 = Ws[kk][tx*4+3];
        acc[0][0] += a0*q0; acc[0][1] += a0*q1; acc[0][2] += a0*q2; acc[0][3] += a0*q3;
        acc[1][0] += a1*q0; acc[1][1] += a1*q1; acc[1][2] += a1*q2; acc[1][3] += a1*q3;
        acc[2][0] += a2*q0; acc[2][1] += a2*q1; acc[2][2] += a2*q2; acc[2][3] += a2*q3;
        acc[3][0] += a3*q0; acc[3][1] += a3*q1; acc[3][2] += a3*q2; acc[3][3] += a3*q3;
      }
    }
    #pragma unroll
    for (int i = 0; i < 4; ++i) {
      float p = 0.f;
      #pragma unroll
      for (int j = 0; j < 4; ++j) {
        int n = nt * 64 + tx * 4 + j;
        float h = acc[i][j] + b1[n]; h = fmaxf(h, 0.f);
        p += h * w2[n];
      }
      atomicAdd(&outacc[ty * 4 + i], p);
    }
  }
  __syncthreads();
  if (tid < 64 && (ebase + tid) < E) out[ebase + tid] = outacc[tid] + b2[0];
}

extern "C" void kernel_launch(void* const* d_in, const int* in_sizes, int n_in,
                              void* d_out, int out_size, void* d_ws, size_t ws_size,
                              hipStream_t stream)
{
  const float* z_user  = (const float*)d_in[0];
  const float* z_movie = (const float*)d_in[1];
  const int*   erow    = (const int*)d_in[2];
  const int*   ecol    = (const int*)d_in[3];
  const float* w1      = (const float*)d_in[4];
  const float* b1      = (const float*)d_in[5];
  const float* w2      = (const float*)d_in[6];
  const float* b2      = (const float*)d_in[7];
  float* out = (float*)d_out;

  const int NU = in_sizes[0] / HDIM;   // 100000
  const int NM = in_sizes[1] / HDIM;   // 50000
  const int E  = in_sizes[2];          // 500000
  const int NB = (NM + 1023) / 1024;   // scan blocks (49)

  const size_t shorts = (size_t)(NU + NM) * HDIM + (size_t)1024 * 512;
  const size_t need_basic  = shorts * 2;
  const size_t need_sorted = shorts * 2 + ((size_t)3 * NM + 1 + (size_t)2 * E + NB + 64) * 4;

  if (ws_size >= need_basic) {
    unsigned short* u1  = (unsigned short*)d_ws;
    unsigned short* m1  = u1 + (size_t)NU * HDIM;
    unsigned short* w1t = m1 + (size_t)NM * HDIM;
    if (ws_size >= need_sorted) {
      int* cnt  = (int*)(w1t + (size_t)1024 * 512);
      int* ptr  = cnt + NM;
      int* cur  = ptr + NM + 1;
      int* srow = cur + NM;
      int* seid = srow + E;
      int* bsum = seid + E;
      k_w1t<<<(1024 * 512) / 256, 256, 0, stream>>>(w1, w1t, cnt, NM);
      k_hist<<<(E + 255) / 256, 256, 0, stream>>>(ecol, cnt, E);
      k_scan1<<<NB, 1024, 0, stream>>>(cnt, bsum, NM);
      k_scan2<<<1, 64, 0, stream>>>(bsum, ptr, NB, NM);
      k_scan3<<<NB, 1024, 0, stream>>>(cnt, bsum, ptr, cur, NM);
      k_scatter<<<(E + 255) / 256, 256, 0, stream>>>(erow, ecol, cur, srow, seid, E);
      k_gemm<<<dim3(HDIM / BN, (NU + BM - 1) / BM), 512, 0, stream>>>(z_user,  NU, w1t, 0,   u1);
      k_gemm<<<dim3(HDIM / BN, (NM + BM - 1) / BM), 512, 0, stream>>>(z_movie, NM, w1t, 512, m1);
      k_edge_g<<<2048, 256, 0, stream>>>(ptr, srow, seid, u1, m1, b1, w2, b2, out, NM);
    } else {
      k_w1t<<<(1024 * 512) / 256, 256, 0, stream>>>(w1, w1t, (int*)d_ws, 0);
      k_gemm<<<dim3(HDIM / BN, (NU + BM - 1) / BM), 512, 0, stream>>>(z_user,  NU, w1t, 0,   u1);
      k_gemm<<<dim3(HDIM / BN, (NM + BM - 1) / BM), 512, 0, stream>>>(z_movie, NM, w1t, 512, m1);
      k_edge<<<2048, 256, 0, stream>>>(erow, ecol, u1, m1, b1, w2, b2, out, E);
    }
  } else {
    k_fallback<<<(E + 63) / 64, 256, 0, stream>>>(z_user, z_movie, erow, ecol, w1, b1, w2, b2, out, E);
  }
}